// Round 3
// baseline (601.581 us; speedup 1.0000x reference)
//
#include <hip/hip_runtime.h>

#define TT 2048
#define BB 16
#define DD 1024
#define BD (BB * DD)   // 16384

typedef _Float16 f16;
typedef _Float16 f16x8 __attribute__((ext_vector_type(8)));
typedef float f32x4 __attribute__((ext_vector_type(4)));
typedef float f32x2 __attribute__((ext_vector_type(2)));
typedef unsigned int u32;

// async global->LDS, 16B per lane. LDS dest = wave-uniform base + lane*16.
__device__ __forceinline__ void gload_lds16(const void* g, const void* s) {
    const __attribute__((address_space(1))) u32* gp =
        (const __attribute__((address_space(1))) u32*)(unsigned long long)(size_t)g;
    __attribute__((address_space(3))) u32* sp =
        (__attribute__((address_space(3))) u32*)(u32)(size_t)s;
    __builtin_amdgcn_global_load_lds(gp, sp, 16, 0, 0);
}

// ---------------------------------------------------------------------------
// fp32 -> fp16 convert (8 elems/thread/iter, grid-stride)
// ---------------------------------------------------------------------------
__global__ __launch_bounds__(256) void cvt_f16(const float* __restrict__ in,
                                               f16* __restrict__ out, int n8) {
    int i = blockIdx.x * 256 + threadIdx.x;
    const int stride = gridDim.x * 256;
    for (; i < n8; i += stride) {
        const float4* p = (const float4*)in + (size_t)i * 2;
        float4 a = p[0], b = p[1];
        f16x8 o;
        o[0] = (f16)a.x; o[1] = (f16)a.y; o[2] = (f16)a.z; o[3] = (f16)a.w;
        o[4] = (f16)b.x; o[5] = (f16)b.y; o[6] = (f16)b.z; o[7] = (f16)b.w;
        *((f16x8*)out + i) = o;
    }
}

// ---------------------------------------------------------------------------
// MFMA GEMM: C[m,n] = sum_k A[m,k]*W[n,k], fp16 in / fp32 out.
// 128x128 block tile, BK=64, 256 threads = 4 waves (2x2), wave tile 64x64
// = 4x4 MFMA 16x16x32. LDS layout: row-major [128 rows][8 slots][8 f16],
// slot index XOR-swizzled by (row&7) to avoid bank conflicts on frag reads.
//
// XCD swizzle: default dispatch round-robins flat block ids over 8 XCDs, so
// the 8 bn-blocks sharing one A-tile land on 8 different L2s (A fetched 8x
// from LLC). Remap so each XCD owns a contiguous bm range with all 8 bn:
// A-tile is L2-hit for 7/8 reads; W (2 MB) stays resident in each XCD's L2.
// Bijective: nwg = 8 * nbm, nbm % 8 == 0 (tc multiple of 64 -> nbm = tc/8).
// ---------------------------------------------------------------------------
__global__ __launch_bounds__(256) void gemm_f16(const f16* __restrict__ A,
                                                const f16* __restrict__ W,
                                                float* __restrict__ C) {
    __shared__ f16 As[128 * 64];
    __shared__ f16 Bs[128 * 64];

    const int tid = threadIdx.x;

    const int flat = blockIdx.y * gridDim.x + blockIdx.x;  // gridDim.x == 8
    const int xcd = flat & 7;
    const int j = flat >> 3;                 // 0 .. nbm*8/8-1 = 0..nwg/8-1
    const int rows_per_xcd = gridDim.y >> 3; // nbm/8
    const int bm = (xcd * rows_per_xcd + (j >> 3)) * 128;
    const int bn = (j & 7) * 128;

    // staging: chunk c = r*256+tid -> row = c>>3 (r*32 + tid>>3), slot = c&7.
    // stored slot s holds global k-chunk kb = s ^ (row&7); since rows step by
    // 32 per round, (row&7) and hence kb are round-invariant.
    const int sm = tid >> 3;            // base row 0..31
    const int ss = tid & 7;             // slot
    const int kb = ss ^ (sm & 7);       // global k-chunk fetched by this lane

    const f16* Ag = A + (size_t)(bm + sm) * DD + kb * 8;
    const f16* Bg = W + (size_t)(bn + sm) * DD + kb * 8;

    const int wave = tid >> 6;
    const int lane = tid & 63;
    const int wm = (wave & 1) * 64;
    const int wn = (wave >> 1) * 64;
    const int fr = lane & 15;
    const int quad = lane >> 4;

    f32x4 acc[4][4];
#pragma unroll
    for (int i = 0; i < 4; ++i)
#pragma unroll
        for (int j2 = 0; j2 < 4; ++j2) acc[i][j2] = (f32x4){0.f, 0.f, 0.f, 0.f};

    for (int kt = 0; kt < 16; ++kt) {
        const f16* Agk = Ag + kt * 64;
        const f16* Bgk = Bg + kt * 64;
        __syncthreads();   // all waves done reading previous tile
#pragma unroll
        for (int r = 0; r < 4; ++r) {
            gload_lds16(Agk + (size_t)r * 32 * DD, (const char*)As + (r * 256 + tid) * 16);
            gload_lds16(Bgk + (size_t)r * 32 * DD, (const char*)Bs + (r * 256 + tid) * 16);
        }
        __syncthreads();   // compiler drains vmcnt before s_barrier

#pragma unroll
        for (int ks = 0; ks < 2; ++ks) {
            f16x8 af[4], bf[4];
#pragma unroll
            for (int i = 0; i < 4; ++i) {
                const int row = wm + i * 16 + fr;
                const int slot = (ks * 4 + quad) ^ (row & 7);
                af[i] = *(const f16x8*)((const char*)As + row * 128 + slot * 16);
            }
#pragma unroll
            for (int j2 = 0; j2 < 4; ++j2) {
                const int row = wn + j2 * 16 + fr;
                const int slot = (ks * 4 + quad) ^ (row & 7);
                bf[j2] = *(const f16x8*)((const char*)Bs + row * 128 + slot * 16);
            }
#pragma unroll
            for (int i = 0; i < 4; ++i)
#pragma unroll
                for (int j2 = 0; j2 < 4; ++j2)
                    acc[i][j2] = __builtin_amdgcn_mfma_f32_16x16x32_f16(af[i], bf[j2], acc[i][j2], 0, 0, 0);
        }
    }

    // C/D layout: col = lane&15 (n), row = quad*4 + reg (m)
#pragma unroll
    for (int i = 0; i < 4; ++i) {
        const int gm = bm + wm + i * 16 + quad * 4;
#pragma unroll
        for (int j2 = 0; j2 < 4; ++j2) {
            const int gn = bn + wn + j2 * 16 + fr;
            float* cp = C + (size_t)gm * DD + gn;
#pragma unroll
            for (int r = 0; r < 4; ++r)
                cp[(size_t)r * DD] = acc[i][j2][r];
        }
    }
}

// ---------------------------------------------------------------------------
// Scan: 16384 independent recurrences, now 2 chains per thread (float2).
// 8192 threads = 128 waves, 1 wave/SIMD max -> zero TLP, so wall/step =
// instruction issue + unhidden h-chain dependency latency. Two independent
// chains per thread interleave to hide each other's dep latency, and the
// 64-bit address arithmetic + store issue amortizes over 2 chains (8B/lane
// coalesced f32x2 accesses, 512B/wave).
//
// vmcnt accounting (6-bit, in-order retire): depth-16 double buffer keeps
// the awaited load batch's younger-op count at <= 48 (32 stores + 16 loads)
// so the compiler's wait is precise and never forces streaming-store drain.
//
// Pre-scaling: va = 2*(x+b), d2 = 2*dc moves the "2*a" mul off the serial
// h-dependency chain (fmaf -> expf -> add -> rcp -> fmaf).
// ---------------------------------------------------------------------------
__device__ __forceinline__ void cell2(f32x2 v, f32x2 d2, f32x2& h, f32x2& o) {
#pragma unroll
    for (int c = 0; c < 2; ++c) {
        const float z = fmaf(d2[c], h[c], v[c]);               // 2a
        const float E = __expf(z);                              // exp(2a)
        const float t = fmaf(-2.f, __builtin_amdgcn_rcpf(E + 1.f), 1.f); // tanh(a)
        h[c] = t;
        const float s = __builtin_amdgcn_rcpf(1.f + __expf(-t)); // sigmoid
        o[c] = t * t * s;
    }
}

__global__ __launch_bounds__(64) void scan_step(const float* __restrict__ xw,
                                                const float* __restrict__ dvec,
                                                const float* __restrict__ bvec,
                                                const float* __restrict__ h0,
                                                float* __restrict__ out,
                                                float* __restrict__ hout,
                                                int Tc, int first) {
    const int p = blockIdx.x * 64 + threadIdx.x;   // pair index
    const int l = p * 2;
    const int e = l & (DD - 1);

    const f32x2 dv = *(const f32x2*)(dvec + e);
    const f32x2 bv = *(const f32x2*)(bvec + e);
    f32x2 d2, b2;
    d2.x = 2.f * fminf(fmaxf(dv.x, -0.99f), 0.99f);
    d2.y = 2.f * fminf(fmaxf(dv.y, -0.99f), 0.99f);
    b2.x = 2.f * bv.x;
    b2.y = 2.f * bv.y;

    f32x2 h;
    if (first) {
        h = *(const f32x2*)(h0 + l);
        *(f32x2*)(hout + l) = h;
    } else {
        h = *(const f32x2*)(hout + l);
    }

    const float* xp = xw + l;
    f32x2 va[16], vb[16];
#pragma unroll
    for (int i = 0; i < 16; ++i) {
        f32x2 x = *(const f32x2*)(xp + (size_t)i * BD);
        va[i] = x + x + b2;   // 2*(x+b)
    }

    for (int t0 = 0; t0 < Tc; t0 += 32) {
        // prefetch t0+16 .. t0+31
#pragma unroll
        for (int i = 0; i < 16; ++i) {
            f32x2 x = *(const f32x2*)(xp + (size_t)(t0 + 16 + i) * BD);
            vb[i] = x + x + b2;
        }
        // compute t0 .. t0+15 (wait = vmcnt(16): only vb loads are younger)
#pragma unroll
        for (int i = 0; i < 16; ++i) {
            f32x2 o;
            cell2(va[i], d2, h, o);
            __builtin_nontemporal_store(o, (f32x2*)(out + (size_t)(t0 + i) * BD + l));
            __builtin_nontemporal_store(h, (f32x2*)(hout + (size_t)(t0 + i + 1) * BD + l));
        }
        // prefetch t0+32 .. t0+47
        if (t0 + 32 < Tc) {
#pragma unroll
            for (int i = 0; i < 16; ++i) {
                f32x2 x = *(const f32x2*)(xp + (size_t)(t0 + 32 + i) * BD);
                va[i] = x + x + b2;
            }
        }
        // compute t0+16 .. t0+31 (wait = vmcnt(48): 32 stores + 16 loads younger)
#pragma unroll
        for (int i = 0; i < 16; ++i) {
            f32x2 o;
            cell2(vb[i], d2, h, o);
            __builtin_nontemporal_store(o, (f32x2*)(out + (size_t)(t0 + 16 + i) * BD + l));
            __builtin_nontemporal_store(h, (f32x2*)(hout + (size_t)(t0 + 16 + i + 1) * BD + l));
        }
    }
}

// ---------------------------------------------------------------------------
extern "C" void kernel_launch(void* const* d_in, const int* in_sizes, int n_in,
                              void* d_out, int out_size, void* d_ws, size_t ws_size,
                              hipStream_t stream) {
    const float* x  = (const float*)d_in[0];   // [T,B,D]
    const float* h0 = (const float*)d_in[1];   // [B,D]
    const float* Wx = (const float*)d_in[2];   // [D,D]
    const float* dv = (const float*)d_in[3];   // [D]
    const float* bv = (const float*)d_in[4];   // [D]

    float* out  = (float*)d_out;               // [T,B,D]
    float* hout = out + (size_t)TT * BD;       // [T+1,B,D]

    // ws layout: [W_f16 2MB][x_f16 Tc*BD*2][xw fp32 Tc*BD*4]
    f16* Wf = (f16*)d_ws;
    const size_t wbytes = (size_t)DD * DD * sizeof(f16);
    const size_t rem = (ws_size > wbytes) ? ws_size - wbytes : 0;
    long long Tc = (long long)(rem / ((size_t)BD * 6));
    Tc = (Tc / 64) * 64;
    if (Tc > TT) Tc = TT;
    if (Tc < 64) Tc = 64;

    f16*   xf = (f16*)((char*)d_ws + wbytes);
    float* xw = (float*)((char*)d_ws + wbytes + (size_t)Tc * BD * 2);

    cvt_f16<<<512, 256, 0, stream>>>(Wx, Wf, DD * DD / 8);

    for (int t0 = 0; t0 < TT; ) {
        int tc = (int)Tc;
        if (tc > TT - t0) tc = TT - t0;
        const int n8 = tc * BD / 8;
        cvt_f16<<<2048, 256, 0, stream>>>(x + (size_t)t0 * BD, xf, n8);
        dim3 grid(DD / 128, tc * BB / 128);
        gemm_f16<<<grid, 256, 0, stream>>>(xf, Wf, xw);
        scan_step<<<BD / 128, 64, 0, stream>>>(xw, dv, bv, h0,
                                               out  + (size_t)t0 * BD,
                                               hout + (size_t)t0 * BD,
                                               tc, t0 == 0);
        t0 += tc;
    }
}

// Round 5
// 513.991 us; speedup vs baseline: 1.1704x; 1.1704x over previous
//
#include <hip/hip_runtime.h>

#define TT 2048
#define BB 16
#define DD 1024
#define BD (BB * DD)   // 16384
#define SLAB 16

typedef _Float16 f16;
typedef _Float16 f16x8 __attribute__((ext_vector_type(8)));
typedef float f32x4 __attribute__((ext_vector_type(4)));
typedef unsigned int u32;

// async global->LDS, 16B per lane. LDS dest = wave-uniform base + lane*16.
__device__ __forceinline__ void gload_lds16(const void* g, const void* s) {
    const __attribute__((address_space(1))) u32* gp =
        (const __attribute__((address_space(1))) u32*)(unsigned long long)(size_t)g;
    __attribute__((address_space(3))) u32* sp =
        (__attribute__((address_space(3))) u32*)(u32)(size_t)s;
    __builtin_amdgcn_global_load_lds(gp, sp, 16, 0, 0);
}

// ---------------------------------------------------------------------------
// fp32 -> fp16 convert (8 elems/thread/iter, grid-stride)
// ---------------------------------------------------------------------------
__global__ __launch_bounds__(256) void cvt_f16(const float* __restrict__ in,
                                               f16* __restrict__ out, int n8) {
    int i = blockIdx.x * 256 + threadIdx.x;
    const int stride = gridDim.x * 256;
    for (; i < n8; i += stride) {
        const float4* p = (const float4*)in + (size_t)i * 2;
        float4 a = p[0], b = p[1];
        f16x8 o;
        o[0] = (f16)a.x; o[1] = (f16)a.y; o[2] = (f16)a.z; o[3] = (f16)a.w;
        o[4] = (f16)b.x; o[5] = (f16)b.y; o[6] = (f16)b.z; o[7] = (f16)b.w;
        *((f16x8*)out + i) = o;
    }
}

// ---------------------------------------------------------------------------
// MFMA GEMM: C[m,n] = sum_k A[m,k]*W[n,k], fp16 in / fp32 out.
// 128x128 block tile, BK=64, 256 threads = 4 waves (2x2), wave tile 64x64
// = 4x4 MFMA 16x16x32. LDS layout: row-major [128 rows][8 slots][8 f16],
// slot index XOR-swizzled by (row&7) to avoid bank conflicts on frag reads.
//
// XCD swizzle (kept from R3): each XCD owns a contiguous bm range with all
// 8 bn so A-tiles are L2-hits for 7/8 reads and W stays L2-resident.
// ---------------------------------------------------------------------------
__global__ __launch_bounds__(256) void gemm_f16(const f16* __restrict__ A,
                                                const f16* __restrict__ W,
                                                float* __restrict__ C) {
    __shared__ f16 As[128 * 64];
    __shared__ f16 Bs[128 * 64];

    const int tid = threadIdx.x;

    const int flat = blockIdx.y * gridDim.x + blockIdx.x;  // gridDim.x == 8
    const int xcd = flat & 7;
    const int j = flat >> 3;
    const int rows_per_xcd = gridDim.y >> 3;
    const int bm = (xcd * rows_per_xcd + (j >> 3)) * 128;
    const int bn = (j & 7) * 128;

    const int sm = tid >> 3;            // base row 0..31
    const int ss = tid & 7;             // slot
    const int kb = ss ^ (sm & 7);       // global k-chunk fetched by this lane

    const f16* Ag = A + (size_t)(bm + sm) * DD + kb * 8;
    const f16* Bg = W + (size_t)(bn + sm) * DD + kb * 8;

    const int wave = tid >> 6;
    const int lane = tid & 63;
    const int wm = (wave & 1) * 64;
    const int wn = (wave >> 1) * 64;
    const int fr = lane & 15;
    const int quad = lane >> 4;

    f32x4 acc[4][4];
#pragma unroll
    for (int i = 0; i < 4; ++i)
#pragma unroll
        for (int j2 = 0; j2 < 4; ++j2) acc[i][j2] = (f32x4){0.f, 0.f, 0.f, 0.f};

    for (int kt = 0; kt < 16; ++kt) {
        const f16* Agk = Ag + kt * 64;
        const f16* Bgk = Bg + kt * 64;
        __syncthreads();
#pragma unroll
        for (int r = 0; r < 4; ++r) {
            gload_lds16(Agk + (size_t)r * 32 * DD, (const char*)As + (r * 256 + tid) * 16);
            gload_lds16(Bgk + (size_t)r * 32 * DD, (const char*)Bs + (r * 256 + tid) * 16);
        }
        __syncthreads();

#pragma unroll
        for (int ks = 0; ks < 2; ++ks) {
            f16x8 af[4], bf[4];
#pragma unroll
            for (int i = 0; i < 4; ++i) {
                const int row = wm + i * 16 + fr;
                const int slot = (ks * 4 + quad) ^ (row & 7);
                af[i] = *(const f16x8*)((const char*)As + row * 128 + slot * 16);
            }
#pragma unroll
            for (int j2 = 0; j2 < 4; ++j2) {
                const int row = wn + j2 * 16 + fr;
                const int slot = (ks * 4 + quad) ^ (row & 7);
                bf[j2] = *(const f16x8*)((const char*)Bs + row * 128 + slot * 16);
            }
#pragma unroll
            for (int i = 0; i < 4; ++i)
#pragma unroll
                for (int j2 = 0; j2 < 4; ++j2)
                    acc[i][j2] = __builtin_amdgcn_mfma_f32_16x16x32_f16(af[i], bf[j2], acc[i][j2], 0, 0, 0);
        }
    }

    // C/D layout: col = lane&15 (n), row = quad*4 + reg (m)
#pragma unroll
    for (int i = 0; i < 4; ++i) {
        const int gm = bm + wm + i * 16 + quad * 4;
#pragma unroll
        for (int j2 = 0; j2 < 4; ++j2) {
            const int gn = bn + wn + j2 * 16 + fr;
            float* cp = C + (size_t)gm * DD + gn;
#pragma unroll
            for (int r = 0; r < 4; ++r)
                cp[(size_t)r * DD] = acc[i][j2][r];
        }
    }
}

// ---------------------------------------------------------------------------
// Scan, producer-consumer: 256 blocks x 128 threads (2 waves).
//   wave0 (scan): 64 chains, pure-load vmem stream, quad-buffered depth-16
//     register prefetch (lead = 48 steps ~ 2000cy >> ~900cy HBM latency;
//     precise vmcnt(48) waits, no store acks in the counter). Computes
//     tanh-cell + silu-gate, writes (o,h) slabs to a 2-deep LDS ring.
//   wave1 (storer): after each barrier, streams the previous slab from LDS
//     to out/hout with nontemporal stores (its own vmcnt, fire-and-forget).
// Race-freedom: in window between barriers k,k+1 scan writes parity k&1,
// storer reads parity (k-1)&1 -> disjoint. Both waves hit exactly S barriers.
// Sigmoid on tanh-output t in (-1,1) via odd Taylor-7 poly (max err ~2e-5,
// tolerance 3.9e-3): removes one v_exp + one v_rcp (16cy/step wave64 issue).
// ---------------------------------------------------------------------------
__global__ __launch_bounds__(128) void scan_step(const float* __restrict__ xw,
                                                 const float* __restrict__ dvec,
                                                 const float* __restrict__ bvec,
                                                 const float* __restrict__ h0,
                                                 float* __restrict__ out,
                                                 float* __restrict__ hout,
                                                 int Tc, int first) {
    __shared__ float o_lds[2][SLAB][64];
    __shared__ float h_lds[2][SLAB][64];

    const int lane = threadIdx.x & 63;
    const int wid  = threadIdx.x >> 6;
    const int c0   = blockIdx.x * 64;
    const int l    = c0 + lane;
    const int S    = Tc / SLAB;          // Tc multiple of 64 -> S multiple of 4

    if (wid == 0) {
        // ---------------- scan wave ----------------
        const int e = l & (DD - 1);
        const float dc = fminf(fmaxf(dvec[e], -0.99f), 0.99f);
        const float d2 = 2.f * dc;
        const float b2 = 2.f * bvec[e];

        float h = first ? h0[l] : hout[l];

        const float* xp = xw + l;
        float A[SLAB], B[SLAB], C[SLAB], D[SLAB];

#define LOADSLAB(buf, s_) do {                                          \
        const float* _p = xp + (size_t)(s_) * SLAB * BD;                \
        _Pragma("unroll")                                               \
        for (int _i = 0; _i < SLAB; ++_i) buf[_i] = _p[(size_t)_i * BD]; \
    } while (0)

#define COMPUTE(buf, par) do {                                          \
        _Pragma("unroll")                                               \
        for (int _i = 0; _i < SLAB; ++_i) {                             \
            const float v2 = fmaf(2.f, buf[_i], b2);                    \
            const float z  = fmaf(d2, h, v2);        /* 2a */           \
            const float E  = __expf(z);                                 \
            const float t  = fmaf(-2.f, __builtin_amdgcn_rcpf(E + 1.f), 1.f); \
            h = t;                                                      \
            const float t2 = t * t;                                     \
            const float pp = fmaf(t2, fmaf(t2, fmaf(t2, -2.108134e-4f,  \
                                2.0833334e-3f), -2.0833334e-2f), 0.25f);\
            const float sg = fmaf(t, pp, 0.5f);      /* sigmoid(t) */   \
            o_lds[par][_i][lane] = t2 * sg;                             \
            h_lds[par][_i][lane] = t;                                   \
        }                                                               \
    } while (0)

        LOADSLAB(A, 0); LOADSLAB(B, 1); LOADSLAB(C, 2);
        for (int s = 0; s < S; s += 4) {
            if (s + 3 < S) LOADSLAB(D, s + 3);
            COMPUTE(A, 0);
            __syncthreads();
            if (s + 4 < S) LOADSLAB(A, s + 4);
            COMPUTE(B, 1);
            __syncthreads();
            if (s + 5 < S) LOADSLAB(B, s + 5);
            COMPUTE(C, 0);
            __syncthreads();
            if (s + 6 < S) LOADSLAB(C, s + 6);
            COMPUTE(D, 1);
            __syncthreads();
        }
#undef LOADSLAB
#undef COMPUTE
    } else {
        // ---------------- storer wave ----------------
        if (first) {
            // h row 0 = h0 (scan wave keeps a pure-load vmem stream)
            __builtin_nontemporal_store(h0[l], hout + l);
        }
        for (int s = 0; s < S; ++s) {
            __syncthreads();             // slab s is now in lds[s&1]
            const int par = s & 1;
            float* po = out  + (size_t)(s * SLAB) * BD + l;
            float* ph = hout + (size_t)(s * SLAB + 1) * BD + l;
#pragma unroll
            for (int t = 0; t < SLAB; ++t) {
                const float ov = o_lds[par][t][lane];
                const float hv = h_lds[par][t][lane];
                __builtin_nontemporal_store(ov, po + (size_t)t * BD);
                __builtin_nontemporal_store(hv, ph + (size_t)t * BD);
            }
        }
    }
}

// ---------------------------------------------------------------------------
extern "C" void kernel_launch(void* const* d_in, const int* in_sizes, int n_in,
                              void* d_out, int out_size, void* d_ws, size_t ws_size,
                              hipStream_t stream) {
    const float* x  = (const float*)d_in[0];   // [T,B,D]
    const float* h0 = (const float*)d_in[1];   // [B,D]
    const float* Wx = (const float*)d_in[2];   // [D,D]
    const float* dv = (const float*)d_in[3];   // [D]
    const float* bv = (const float*)d_in[4];   // [D]

    float* out  = (float*)d_out;               // [T,B,D]
    float* hout = out + (size_t)TT * BD;       // [T+1,B,D]

    // ws layout: [W_f16 2MB][x_f16 Tc*BD*2][xw fp32 Tc*BD*4]
    f16* Wf = (f16*)d_ws;
    const size_t wbytes = (size_t)DD * DD * sizeof(f16);
    const size_t rem = (ws_size > wbytes) ? ws_size - wbytes : 0;
    long long Tc = (long long)(rem / ((size_t)BD * 6));
    Tc = (Tc / 64) * 64;
    if (Tc > TT) Tc = TT;
    if (Tc < 64) Tc = 64;

    f16*   xf = (f16*)((char*)d_ws + wbytes);
    float* xw = (float*)((char*)d_ws + wbytes + (size_t)Tc * BD * 2);

    cvt_f16<<<512, 256, 0, stream>>>(Wx, Wf, DD * DD / 8);

    for (int t0 = 0; t0 < TT; ) {
        int tc = (int)Tc;
        if (tc > TT - t0) tc = TT - t0;
        const int n8 = tc * BD / 8;
        cvt_f16<<<2048, 256, 0, stream>>>(x + (size_t)t0 * BD, xf, n8);
        dim3 grid(DD / 128, tc * BB / 128);
        gemm_f16<<<grid, 256, 0, stream>>>(xf, Wf, xw);
        scan_step<<<BD / 64, 128, 0, stream>>>(xw, dv, bv, h0,
                                               out  + (size_t)t0 * BD,
                                               hout + (size_t)t0 * BD,
                                               tc, t0 == 0);
        t0 += tc;
    }
}

// Round 6
// 507.467 us; speedup vs baseline: 1.1855x; 1.0129x over previous
//
#include <hip/hip_runtime.h>

#define TT 2048
#define BB 16
#define DD 1024
#define BD (BB * DD)   // 16384
#define SLAB 16

typedef _Float16 f16;
typedef _Float16 f16x8 __attribute__((ext_vector_type(8)));
typedef float f32x4 __attribute__((ext_vector_type(4)));
typedef unsigned int u32;

// async global->LDS, 16B per lane. LDS dest = wave-uniform base + lane*16.
__device__ __forceinline__ void gload_lds16(const void* g, const void* s) {
    const __attribute__((address_space(1))) u32* gp =
        (const __attribute__((address_space(1))) u32*)(unsigned long long)(size_t)g;
    __attribute__((address_space(3))) u32* sp =
        (__attribute__((address_space(3))) u32*)(u32)(size_t)s;
    __builtin_amdgcn_global_load_lds(gp, sp, 16, 0, 0);
}

// ---------------------------------------------------------------------------
// fp32 -> fp16 convert, W and x fused into one launch (one fewer gap).
// Blocks [0,64): W (first chunk only, win != nullptr). Blocks [64,N): x.
// ---------------------------------------------------------------------------
__device__ __forceinline__ void cvt8(const float* __restrict__ in,
                                     f16* __restrict__ out, int i) {
    const float4* p = (const float4*)in + (size_t)i * 2;
    float4 a = p[0], b = p[1];
    f16x8 o;
    o[0] = (f16)a.x; o[1] = (f16)a.y; o[2] = (f16)a.z; o[3] = (f16)a.w;
    o[4] = (f16)b.x; o[5] = (f16)b.y; o[6] = (f16)b.z; o[7] = (f16)b.w;
    *((f16x8*)out + i) = o;
}

__global__ __launch_bounds__(256) void cvt_both(const float* __restrict__ xin,
                                                f16* __restrict__ xout, int n8x,
                                                const float* __restrict__ win,
                                                f16* __restrict__ wout, int n8w) {
    if (blockIdx.x < 64) {
        if (win) {
            int i = blockIdx.x * 256 + threadIdx.x;
            for (; i < n8w; i += 64 * 256) cvt8(win, wout, i);
        }
    } else {
        int i = (blockIdx.x - 64) * 256 + threadIdx.x;
        const int stride = (gridDim.x - 64) * 256;
        for (; i < n8x; i += stride) cvt8(xin, xout, i);
    }
}

// ---------------------------------------------------------------------------
// MFMA GEMM v2: C[m,n] = sum_k A[m,k]*W[n,k], fp16 in / fp32 out.
// 256x128 block tile, BK=64, 256 threads = 4 waves (2M x 2N), wave tile
// 128x64 = 8x4 MFMA 16x16x32, acc 128 VGPR.
//
// WHY wider wave-tile: LDS fragment bytes/FLOP ~ (1/Wm + 1/Wn). The old
// 64x64 wave tile read 16 b128/K-step for 32 MFMA (LDS demand ~400 B/cy/CU
// > 256 B/cy port: LDS-read-bound, MfmaUtil starved). 128x64 reads 24 b128
// for 64 MFMA (-33% LDS/FLOP), and 1024 blocks (vs 2048) halve the
// prologue/epilogue count that the short K=16-step loop can't amortize.
// (32x32x16 MFMA rejected: its 32-row fragment read turns the XOR swizzle
// into a 4-way bank conflict, 1.58x; 16x16 keeps the free 2-way.)
//
// LDS layout: row-major [rows][8 slots][8 f16], slot XOR-swizzled by
// (row&7); staging pre-swizzles the global k-chunk so LDS dest is linear.
// XCD swizzle: each XCD owns a contiguous bm range with all 8 bn so
// A-tiles are L2-hits and W stays L2-resident; identity fallback when
// gridDim.y % 8 != 0 (small-Tc tails) for correctness.
// ---------------------------------------------------------------------------
__global__ __launch_bounds__(256, 2) void gemm_f16(const f16* __restrict__ A,
                                                   const f16* __restrict__ W,
                                                   float* __restrict__ C) {
    __shared__ f16 As[256 * 64];
    __shared__ f16 Bs[128 * 64];

    const int tid = threadIdx.x;

    int bmi, bni;
    if ((gridDim.y & 7) == 0) {
        const int flat = blockIdx.y * gridDim.x + blockIdx.x;  // gridDim.x == 8
        const int xcd = flat & 7;
        const int j = flat >> 3;
        const int rows_per_xcd = gridDim.y >> 3;
        bmi = xcd * rows_per_xcd + (j >> 3);
        bni = j & 7;
    } else {
        bmi = blockIdx.y;
        bni = blockIdx.x;
    }
    const int bm = bmi * 256;
    const int bn = bni * 128;

    // staging: chunk c = r*256+tid -> row = r*32 + (tid>>3), slot = tid&7.
    // stored slot s holds global k-chunk kb = s ^ (row&7); rows step by 32
    // per round so (row&7) and hence kb are round-invariant.
    const int sm = tid >> 3;            // base row 0..31
    const int ss = tid & 7;             // slot
    const int kb = ss ^ (sm & 7);       // global k-chunk fetched by this lane

    const f16* Ag = A + (size_t)(bm + sm) * DD + kb * 8;
    const f16* Bg = W + (size_t)(bn + sm) * DD + kb * 8;

    const int wave = tid >> 6;
    const int lane = tid & 63;
    const int wm = (wave & 1) * 128;    // M-half: 0 or 128
    const int wn = (wave >> 1) * 64;    // N-half: 0 or 64
    const int fr = lane & 15;
    const int quad = lane >> 4;

    f32x4 acc[8][4];
#pragma unroll
    for (int i = 0; i < 8; ++i)
#pragma unroll
        for (int j2 = 0; j2 < 4; ++j2) acc[i][j2] = (f32x4){0.f, 0.f, 0.f, 0.f};

    for (int kt = 0; kt < 16; ++kt) {
        const f16* Agk = Ag + kt * 64;
        const f16* Bgk = Bg + kt * 64;
        __syncthreads();   // all waves done reading previous tile
#pragma unroll
        for (int r = 0; r < 8; ++r)
            gload_lds16(Agk + (size_t)r * 32 * DD, (const char*)As + (r * 256 + tid) * 16);
#pragma unroll
        for (int r = 0; r < 4; ++r)
            gload_lds16(Bgk + (size_t)r * 32 * DD, (const char*)Bs + (r * 256 + tid) * 16);
        __syncthreads();   // compiler drains vmcnt before s_barrier

#pragma unroll
        for (int ks = 0; ks < 2; ++ks) {
            f16x8 af[8], bf[4];
#pragma unroll
            for (int i = 0; i < 8; ++i) {
                const int row = wm + i * 16 + fr;
                const int slot = (ks * 4 + quad) ^ (row & 7);
                af[i] = *(const f16x8*)((const char*)As + row * 128 + slot * 16);
            }
#pragma unroll
            for (int j2 = 0; j2 < 4; ++j2) {
                const int row = wn + j2 * 16 + fr;
                const int slot = (ks * 4 + quad) ^ (row & 7);
                bf[j2] = *(const f16x8*)((const char*)Bs + row * 128 + slot * 16);
            }
#pragma unroll
            for (int i = 0; i < 8; ++i)
#pragma unroll
                for (int j2 = 0; j2 < 4; ++j2)
                    acc[i][j2] = __builtin_amdgcn_mfma_f32_16x16x32_f16(af[i], bf[j2], acc[i][j2], 0, 0, 0);
        }
    }

    // C/D layout: col = lane&15 (n), row = quad*4 + reg (m)
#pragma unroll
    for (int i = 0; i < 8; ++i) {
        const int gm = bm + wm + i * 16 + quad * 4;
#pragma unroll
        for (int j2 = 0; j2 < 4; ++j2) {
            const int gn = bn + wn + j2 * 16 + fr;
            float* cp = C + (size_t)gm * DD + gn;
#pragma unroll
            for (int r = 0; r < 4; ++r)
                cp[(size_t)r * DD] = acc[i][j2][r];
        }
    }
}

// ---------------------------------------------------------------------------
// Scan, producer-consumer (unchanged from R5 -- verified): 256 blocks x 128
// threads. wave0: pure-load vmem stream, quad-buffered depth-16 register
// prefetch (lead ~2000cy >> ~900cy HBM latency; precise vmcnt waits, no
// store acks). wave1: streams slabs from a 2-deep LDS ring to out/hout with
// nontemporal stores on its own counter. Disjoint parities -> race-free.
// Sigmoid via odd Taylor-7 on tanh-output t in (-1,1) (err ~2e-5).
// ---------------------------------------------------------------------------
__global__ __launch_bounds__(128) void scan_step(const float* __restrict__ xw,
                                                 const float* __restrict__ dvec,
                                                 const float* __restrict__ bvec,
                                                 const float* __restrict__ h0,
                                                 float* __restrict__ out,
                                                 float* __restrict__ hout,
                                                 int Tc, int first) {
    __shared__ float o_lds[2][SLAB][64];
    __shared__ float h_lds[2][SLAB][64];

    const int lane = threadIdx.x & 63;
    const int wid  = threadIdx.x >> 6;
    const int c0   = blockIdx.x * 64;
    const int l    = c0 + lane;
    const int S    = Tc / SLAB;          // Tc multiple of 64 -> S multiple of 4

    if (wid == 0) {
        // ---------------- scan wave ----------------
        const int e = l & (DD - 1);
        const float dc = fminf(fmaxf(dvec[e], -0.99f), 0.99f);
        const float d2 = 2.f * dc;
        const float b2 = 2.f * bvec[e];

        float h = first ? h0[l] : hout[l];

        const float* xp = xw + l;
        float A[SLAB], B[SLAB], C[SLAB], D[SLAB];

#define LOADSLAB(buf, s_) do {                                          \
        const float* _p = xp + (size_t)(s_) * SLAB * BD;                \
        _Pragma("unroll")                                               \
        for (int _i = 0; _i < SLAB; ++_i) buf[_i] = _p[(size_t)_i * BD]; \
    } while (0)

#define COMPUTE(buf, par) do {                                          \
        _Pragma("unroll")                                               \
        for (int _i = 0; _i < SLAB; ++_i) {                             \
            const float v2 = fmaf(2.f, buf[_i], b2);                    \
            const float z  = fmaf(d2, h, v2);        /* 2a */           \
            const float E  = __expf(z);                                 \
            const float t  = fmaf(-2.f, __builtin_amdgcn_rcpf(E + 1.f), 1.f); \
            h = t;                                                      \
            const float t2 = t * t;                                     \
            const float pp = fmaf(t2, fmaf(t2, fmaf(t2, -2.108134e-4f,  \
                                2.0833334e-3f), -2.0833334e-2f), 0.25f);\
            const float sg = fmaf(t, pp, 0.5f);      /* sigmoid(t) */   \
            o_lds[par][_i][lane] = t2 * sg;                             \
            h_lds[par][_i][lane] = t;                                   \
        }                                                               \
    } while (0)

        LOADSLAB(A, 0); LOADSLAB(B, 1); LOADSLAB(C, 2);
        for (int s = 0; s < S; s += 4) {
            if (s + 3 < S) LOADSLAB(D, s + 3);
            COMPUTE(A, 0);
            __syncthreads();
            if (s + 4 < S) LOADSLAB(A, s + 4);
            COMPUTE(B, 1);
            __syncthreads();
            if (s + 5 < S) LOADSLAB(B, s + 5);
            COMPUTE(C, 0);
            __syncthreads();
            if (s + 6 < S) LOADSLAB(C, s + 6);
            COMPUTE(D, 1);
            __syncthreads();
        }
#undef LOADSLAB
#undef COMPUTE
    } else {
        // ---------------- storer wave ----------------
        if (first) {
            // h row 0 = h0 (scan wave keeps a pure-load vmem stream)
            __builtin_nontemporal_store(h0[l], hout + l);
        }
        for (int s = 0; s < S; ++s) {
            __syncthreads();             // slab s is now in lds[s&1]
            const int par = s & 1;
            float* po = out  + (size_t)(s * SLAB) * BD + l;
            float* ph = hout + (size_t)(s * SLAB + 1) * BD + l;
#pragma unroll
            for (int t = 0; t < SLAB; ++t) {
                const float ov = o_lds[par][t][lane];
                const float hv = h_lds[par][t][lane];
                __builtin_nontemporal_store(ov, po + (size_t)t * BD);
                __builtin_nontemporal_store(hv, ph + (size_t)t * BD);
            }
        }
    }
}

// ---------------------------------------------------------------------------
extern "C" void kernel_launch(void* const* d_in, const int* in_sizes, int n_in,
                              void* d_out, int out_size, void* d_ws, size_t ws_size,
                              hipStream_t stream) {
    const float* x  = (const float*)d_in[0];   // [T,B,D]
    const float* h0 = (const float*)d_in[1];   // [B,D]
    const float* Wx = (const float*)d_in[2];   // [D,D]
    const float* dv = (const float*)d_in[3];   // [D]
    const float* bv = (const float*)d_in[4];   // [D]

    float* out  = (float*)d_out;               // [T,B,D]
    float* hout = out + (size_t)TT * BD;       // [T+1,B,D]

    // ws layout: [W_f16 2MB][x_f16 Tc*BD*2][xw fp32 Tc*BD*4]
    f16* Wf = (f16*)d_ws;
    const size_t wbytes = (size_t)DD * DD * sizeof(f16);
    const size_t rem = (ws_size > wbytes) ? ws_size - wbytes : 0;
    long long Tc = (long long)(rem / ((size_t)BD * 6));
    Tc = (Tc / 64) * 64;
    if (Tc > TT) Tc = TT;
    if (Tc < 64) Tc = 64;

    f16*   xf = (f16*)((char*)d_ws + wbytes);
    float* xw = (float*)((char*)d_ws + wbytes + (size_t)Tc * BD * 2);

    for (int t0 = 0; t0 < TT; ) {
        int tc = (int)Tc;
        if (tc > TT - t0) tc = TT - t0;
        const int n8 = tc * BD / 8;
        cvt_both<<<2048 + 64, 256, 0, stream>>>(x + (size_t)t0 * BD, xf, n8,
                                                t0 == 0 ? Wx : nullptr, Wf,
                                                DD * DD / 8);
        // M = tc*BB rows; 256-row tiles. tc is a multiple of 64 -> M%256==0.
        dim3 grid(DD / 128, tc * BB / 256);
        gemm_f16<<<grid, 256, 0, stream>>>(xf, Wf, xw);
        scan_step<<<BD / 64, 128, 0, stream>>>(xw, dv, bv, h0,
                                               out  + (size_t)t0 * BD,
                                               hout + (size_t)t0 * BD,
                                               tc, t0 == 0);
        t0 += tc;
    }
}